// Round 2
// baseline (380.229 us; speedup 1.0000x reference)
//
#include <hip/hip_runtime.h>
#include <hip/hip_bf16.h>

// 3 GRUs (bbox in_dim=4, flow in_dim=2 center-pixel, ego in_dim=3), H=128, B=32, T=64.
// One block per (gru, batch) sequence: 96 blocks x 384 threads.
// Thread g owns Whh row g in registers; h lives in LDS; 2 barriers/step.
// Output dtype: f32 (reference computes/returns float32).

#define HID 128
#define TT  64
#define BB  32

__global__ __launch_bounds__(384) void gru_fused_kernel(
    const float* __restrict__ bbox, const float* __restrict__ flow, const float* __restrict__ ego,
    const float* __restrict__ Wih_b, const float* __restrict__ Whh_b,
    const float* __restrict__ bih_b, const float* __restrict__ bhh_b,
    const float* __restrict__ Wih_f, const float* __restrict__ Whh_f,
    const float* __restrict__ bih_f, const float* __restrict__ bhh_f,
    const float* __restrict__ Wih_e, const float* __restrict__ Whh_e,
    const float* __restrict__ bih_e, const float* __restrict__ bhh_e,
    float* __restrict__ ws)           // ws[3][32][128] f32 partials
{
    const int blk = blockIdx.x;
    const int gru = blk >> 5;         // 0=bbox, 1=flow, 2=ego
    const int b   = blk & 31;
    const int g   = threadIdx.x;      // 0..383

    const float* Wih; const float* Whh; const float* bih; const float* bhh; int D;
    if (gru == 0)      { Wih = Wih_b; Whh = Whh_b; bih = bih_b; bhh = bhh_b; D = 4; }
    else if (gru == 1) { Wih = Wih_f; Whh = Whh_f; bih = bih_f; bhh = bhh_f; D = 2; }
    else               { Wih = Wih_e; Whh = Whh_e; bih = bih_e; bhh = bhh_e; D = 3; }

    // ---- per-thread recurrent weight row (128 f32 in VGPRs, static indexing) ----
    float4 w[32];
    const float4* wrow = reinterpret_cast<const float4*>(Whh + (size_t)g * HID);
    #pragma unroll
    for (int k = 0; k < 32; ++k) w[k] = wrow[k];

    float wih[4] = {0.f, 0.f, 0.f, 0.f};
    for (int d = 0; d < D; ++d) wih[d] = Wih[g * D + d];
    const float bi = bih[g];
    const float bh = bhh[g];

    // ---- LDS state ----
    __shared__ __align__(16) float h_s[HID];
    __shared__ float r_s[HID], z_s[HID], in_s[HID], hn_s[HID];
    __shared__ float x_s[TT][4];      // zero-padded to 4 input dims

    // stage x (zero-pad d >= D so the unrolled gi FMA never sees garbage)
    if (g < TT * 4) {
        const int t = g >> 2, d = g & 3;
        float v = 0.f;
        if (gru == 0) {
            v = bbox[(size_t)(b * TT + t) * 4 + d];
        } else if (gru == 1) {
            if (d < 2) {
                const size_t idx = (((size_t)(b * TT + t) * 128 + 64) * 128 + 64) * 2 + d;
                v = flow[idx];
            }
        } else {
            if (d < 3) v = ego[(size_t)(b * TT + t) * 3 + d];
        }
        x_s[t][d] = v;
    }
    if (g < HID) h_s[g] = 0.f;
    __syncthreads();

    for (int t = 0; t < TT; ++t) {
        // hh_g = bhh[g] + sum_k h[k] * Whh[g,k]   (h broadcast from LDS)
        float acc = bh;
        #pragma unroll
        for (int k = 0; k < 32; ++k) {
            const float4 hv = reinterpret_cast<const float4*>(h_s)[k];
            acc = fmaf(w[k].x, hv.x, acc);
            acc = fmaf(w[k].y, hv.y, acc);
            acc = fmaf(w[k].z, hv.z, acc);
            acc = fmaf(w[k].w, hv.w, acc);
        }
        // ih_g = bih[g] + sum_d x[t,d] * Wih[g,d]
        float gi = bi;
        #pragma unroll
        for (int d = 0; d < 4; ++d) gi = fmaf(wih[d], x_s[t][d], gi);

        if (g < 256) {
            const float gate = 1.f / (1.f + expf(-(gi + acc)));
            if (g < HID) r_s[g] = gate; else z_s[g - HID] = gate;
        } else {
            in_s[g - 256] = gi;
            hn_s[g - 256] = acc;
        }
        __syncthreads();

        if (g < HID) {
            const float r = r_s[g];
            const float z = z_s[g];
            const float n = tanhf(in_s[g] + r * hn_s[g]);
            h_s[g] = (1.f - z) * n + z * h_s[g];
        }
        __syncthreads();
    }

    if (g < HID) ws[((size_t)gru * BB + b) * HID + g] = h_s[g];
}

__global__ void combine_kernel(const float* __restrict__ ws, float* __restrict__ out) {
    const int i = blockIdx.x * blockDim.x + threadIdx.x;
    if (i < BB * HID) {
        out[i] = (ws[i] + ws[BB * HID + i] + ws[2 * BB * HID + i]) * (1.0f / 3.0f);
    }
}

extern "C" void kernel_launch(void* const* d_in, const int* in_sizes, int n_in,
                              void* d_out, int out_size, void* d_ws, size_t ws_size,
                              hipStream_t stream) {
    const float* bbox  = (const float*)d_in[0];
    const float* flow  = (const float*)d_in[1];
    const float* ego   = (const float*)d_in[2];
    const float* Wih_b = (const float*)d_in[3];
    const float* Whh_b = (const float*)d_in[4];
    const float* bih_b = (const float*)d_in[5];
    const float* bhh_b = (const float*)d_in[6];
    const float* Wih_f = (const float*)d_in[7];
    const float* Whh_f = (const float*)d_in[8];
    const float* bih_f = (const float*)d_in[9];
    const float* bhh_f = (const float*)d_in[10];
    const float* Wih_e = (const float*)d_in[11];
    const float* Whh_e = (const float*)d_in[12];
    const float* bih_e = (const float*)d_in[13];
    const float* bhh_e = (const float*)d_in[14];

    float* ws = (float*)d_ws;                       // 3*32*128 f32 = 48 KiB
    float* out = (float*)d_out;                     // 32*128 f32

    gru_fused_kernel<<<dim3(96), dim3(384), 0, stream>>>(
        bbox, flow, ego,
        Wih_b, Whh_b, bih_b, bhh_b,
        Wih_f, Whh_f, bih_f, bhh_f,
        Wih_e, Whh_e, bih_e, bhh_e,
        ws);

    combine_kernel<<<dim3((BB * HID + 255) / 256), dim3(256), 0, stream>>>(ws, out);
}

// Round 3
// 374.805 us; speedup vs baseline: 1.0145x; 1.0145x over previous
//
#include <hip/hip_runtime.h>
#include <hip/hip_bf16.h>

// 3 GRUs (bbox D=4, flow D=2 center-pixel, ego D=3), H=128, B=32, T=64.
// Grid: 96 blocks = (gru, batch). Block: 256 threads = 128 hidden units x 2 K-halves.
// Thread (g, q): owns gate rows g (r), g+128 (z), g+256 (n), K-half q.
//   - 3 accumulators share the h-broadcast LDS loads (3-way ILP on the FMA chain)
//   - half-combine via __shfl_xor(.,1); gates + h-update fully thread-local
//   - ping-pong h buffer -> ONE __syncthreads per step, no gate LDS round-trip
// Output dtype: f32.

#define HID 128
#define TT  64
#define BB  32

__device__ __forceinline__ float sigmoidf_(float x) {
    return 1.0f / (1.0f + __expf(-x) * 0.0f + expf(-x)); // keep precise expf
}

__global__ __launch_bounds__(256, 1) void gru_fused_kernel(
    const float* __restrict__ bbox, const float* __restrict__ flow, const float* __restrict__ ego,
    const float* __restrict__ Wih_b, const float* __restrict__ Whh_b,
    const float* __restrict__ bih_b, const float* __restrict__ bhh_b,
    const float* __restrict__ Wih_f, const float* __restrict__ Whh_f,
    const float* __restrict__ bih_f, const float* __restrict__ bhh_f,
    const float* __restrict__ Wih_e, const float* __restrict__ Whh_e,
    const float* __restrict__ bih_e, const float* __restrict__ bhh_e,
    float* __restrict__ ws)           // ws[3][32][128] f32 partials
{
    const int blk = blockIdx.x;
    const int gru = blk >> 5;         // 0=bbox, 1=flow, 2=ego
    const int b   = blk & 31;
    const int tid = threadIdx.x;      // 0..255
    const int g   = tid >> 1;         // hidden unit 0..127
    const int q   = tid & 1;          // K-half

    const float* Wih; const float* Whh; const float* bih; const float* bhh; int D;
    if (gru == 0)      { Wih = Wih_b; Whh = Whh_b; bih = bih_b; bhh = bhh_b; D = 4; }
    else if (gru == 1) { Wih = Wih_f; Whh = Whh_f; bih = bih_f; bhh = bhh_f; D = 2; }
    else               { Wih = Wih_e; Whh = Whh_e; bih = bih_e; bhh = bhh_e; D = 3; }

    // ---- per-thread weights: 3 gate rows x half-K = 3 x 16 float4 (192 VGPRs) ----
    float4 wr[16], wz[16], wn[16];
    {
        const float4* base = reinterpret_cast<const float4*>(Whh) + q * 16;
        const float4* rowr = base + (size_t)(g        ) * 32;
        const float4* rowz = base + (size_t)(g + HID  ) * 32;
        const float4* rown = base + (size_t)(g + 2*HID) * 32;
        #pragma unroll
        for (int k = 0; k < 16; ++k) { wr[k] = rowr[k]; wz[k] = rowz[k]; wn[k] = rown[k]; }
    }

    float wir[4] = {0,0,0,0}, wiz[4] = {0,0,0,0}, win[4] = {0,0,0,0};
    for (int d = 0; d < D; ++d) {
        wir[d] = Wih[(g        ) * D + d];
        wiz[d] = Wih[(g + HID  ) * D + d];
        win[d] = Wih[(g + 2*HID) * D + d];
    }
    const float bir = bih[g], biz = bih[g + HID], bin = bih[g + 2*HID];
    const float bhr = (q == 0) ? bhh[g]         : 0.f;
    const float bhz = (q == 0) ? bhh[g + HID]   : 0.f;
    const float bhn = (q == 0) ? bhh[g + 2*HID] : 0.f;

    // ---- LDS: ping-pong h + staged x ----
    __shared__ __align__(16) float h_s[2][HID];
    __shared__ __align__(16) float4 x4_s[TT];     // zero-padded to 4 dims

    {   // stage x: 256 threads cover t = tid>>2, d = tid&3
        const int t = tid >> 2, d = tid & 3;
        float v = 0.f;
        if (gru == 0) {
            v = bbox[(size_t)(b * TT + t) * 4 + d];
        } else if (gru == 1) {
            if (d < 2) v = flow[(((size_t)(b * TT + t) * 128 + 64) * 128 + 64) * 2 + d];
        } else {
            if (d < 3) v = ego[(size_t)(b * TT + t) * 3 + d];
        }
        reinterpret_cast<float*>(&x4_s[t])[d] = v;
    }
    if (tid < HID) h_s[0][tid] = 0.f;
    float h_old = 0.f;                 // row g's state, tracked redundantly by both halves
    __syncthreads();

    int cur = 0;
    for (int t = 0; t < TT; ++t) {
        const float4 xv = x4_s[t];

        float ar = bhr, az = bhz, an = bhn;
        const float4* hb = reinterpret_cast<const float4*>(&h_s[cur][q * 64]);
        #pragma unroll
        for (int k = 0; k < 16; ++k) {
            const float4 hv = hb[k];
            ar = fmaf(wr[k].x, hv.x, ar); ar = fmaf(wr[k].y, hv.y, ar);
            ar = fmaf(wr[k].z, hv.z, ar); ar = fmaf(wr[k].w, hv.w, ar);
            az = fmaf(wz[k].x, hv.x, az); az = fmaf(wz[k].y, hv.y, az);
            az = fmaf(wz[k].z, hv.z, az); az = fmaf(wz[k].w, hv.w, az);
            an = fmaf(wn[k].x, hv.x, an); an = fmaf(wn[k].y, hv.y, an);
            an = fmaf(wn[k].z, hv.z, an); an = fmaf(wn[k].w, hv.w, an);
        }
        // combine K-halves (partner lane +/-1, same wave)
        ar += __shfl_xor(ar, 1, 64);
        az += __shfl_xor(az, 1, 64);
        an += __shfl_xor(an, 1, 64);

        float gr = bir, gz = biz, gn = bin;
        gr = fmaf(wir[0], xv.x, gr); gr = fmaf(wir[1], xv.y, gr);
        gr = fmaf(wir[2], xv.z, gr); gr = fmaf(wir[3], xv.w, gr);
        gz = fmaf(wiz[0], xv.x, gz); gz = fmaf(wiz[1], xv.y, gz);
        gz = fmaf(wiz[2], xv.z, gz); gz = fmaf(wiz[3], xv.w, gz);
        gn = fmaf(win[0], xv.x, gn); gn = fmaf(win[1], xv.y, gn);
        gn = fmaf(win[2], xv.z, gn); gn = fmaf(win[3], xv.w, gn);

        const float r = 1.f / (1.f + expf(-(gr + ar)));
        const float z = 1.f / (1.f + expf(-(gz + az)));
        const float n = tanhf(gn + r * an);
        const float h_new = (1.f - z) * n + z * h_old;
        h_old = h_new;

        if (q == 0) h_s[cur ^ 1][g] = h_new;
        __syncthreads();
        cur ^= 1;
    }

    if (q == 0) ws[((size_t)gru * BB + b) * HID + g] = h_old;
}

__global__ void combine_kernel(const float* __restrict__ ws, float* __restrict__ out) {
    const int i = blockIdx.x * blockDim.x + threadIdx.x;
    if (i < BB * HID) {
        out[i] = (ws[i] + ws[BB * HID + i] + ws[2 * BB * HID + i]) * (1.0f / 3.0f);
    }
}

extern "C" void kernel_launch(void* const* d_in, const int* in_sizes, int n_in,
                              void* d_out, int out_size, void* d_ws, size_t ws_size,
                              hipStream_t stream) {
    const float* bbox  = (const float*)d_in[0];
    const float* flow  = (const float*)d_in[1];
    const float* ego   = (const float*)d_in[2];
    const float* Wih_b = (const float*)d_in[3];
    const float* Whh_b = (const float*)d_in[4];
    const float* bih_b = (const float*)d_in[5];
    const float* bhh_b = (const float*)d_in[6];
    const float* Wih_f = (const float*)d_in[7];
    const float* Whh_f = (const float*)d_in[8];
    const float* bih_f = (const float*)d_in[9];
    const float* bhh_f = (const float*)d_in[10];
    const float* Wih_e = (const float*)d_in[11];
    const float* Whh_e = (const float*)d_in[12];
    const float* bih_e = (const float*)d_in[13];
    const float* bhh_e = (const float*)d_in[14];

    float* ws  = (float*)d_ws;     // 3*32*128 f32 = 48 KiB
    float* out = (float*)d_out;    // 32*128 f32

    gru_fused_kernel<<<dim3(96), dim3(256), 0, stream>>>(
        bbox, flow, ego,
        Wih_b, Whh_b, bih_b, bhh_b,
        Wih_f, Whh_f, bih_f, bhh_f,
        Wih_e, Whh_e, bih_e, bhh_e,
        ws);

    combine_kernel<<<dim3((BB * HID + 255) / 256), dim3(256), 0, stream>>>(ws, out);
}